// Round 4
// baseline (88.668 us; speedup 1.0000x reference)
//
#include <hip/hip_runtime.h>
#include <hip/hip_bf16.h>

// Problem constants (from setup_inputs): B=4, N=8192, M=8192, D=3, fp32.
constexpr int B = 4;
constexpr int N = 8192;
constexpr int M = 8192;

constexpr int TN = 256;              // threads per block
constexpr int NQ = 4;                // queries per thread (registers)
constexpr int QB = TN * NQ;          // 1024 queries per block
constexpr int NTILES = N / QB;       // 8
constexpr int CHUNKS = 64;           // split of M -> grid 2048 = 8 blocks/CU
constexpr int CHUNK = M / CHUNKS;    // 128 points per block

// ws layout: [0, 512KB) = prepped point table w; [512KB, 512KB+8MB) = partials
constexpr size_t W_BYTES = (size_t)B * M * sizeof(float4);           // 512 KB
constexpr int    NPART   = B * NTILES * CHUNKS;                      // 2048 blocks
// partial[bid * QB + ql] = min over this block's chunk of (||p||^2 - 2 a.p)

// ---------------------------------------------------------------------------
// Prep: w[b*M+m] = { -2*px, -2*py, -2*pz, ||p||^2 }  (one aligned float4/m,
// wave-uniform in main -> scalar s_load).
// ---------------------------------------------------------------------------
__global__ __launch_bounds__(256) void prep_kernel(const float* __restrict__ point,
                                                   float4* __restrict__ w) {
    int i = blockIdx.x * 256 + threadIdx.x;   // 0 .. B*M-1
    if (i < B * M) {
        float px = point[i * 3 + 0];
        float py = point[i * 3 + 1];
        float pz = point[i * 3 + 2];
        float4 v;
        v.x = -2.0f * px;
        v.y = -2.0f * py;
        v.z = -2.0f * pz;
        v.w = fmaf(px, px, fmaf(py, py, pz * pz));
        w[i] = v;
    }
}

// ---------------------------------------------------------------------------
// Main: identical compute structure to round 3 (NQ=4 queries/thread, 128-point
// chunk, wave-uniform float4 scalar loads, 3.5 VALU/pair). ONLY change:
// plain coalesced store of the raw per-chunk partial min instead of a
// device-scope atomicMin — isolates the atomic-tail hypothesis.
// ---------------------------------------------------------------------------
__global__ __launch_bounds__(256, 8) void main_kernel(const float* __restrict__ input,
                                                      const float4* __restrict__ w,
                                                      float* __restrict__ partial) {
    const int bid   = blockIdx.x;
    const int chunk = bid % CHUNKS;
    const int ntile = (bid / CHUNKS) % NTILES;
    const int b     = bid / (CHUNKS * NTILES);
    const int n0    = ntile * QB + threadIdx.x;   // queries n0 + q*TN

    float a0[NQ], a1[NQ], a2[NQ], r[NQ];
#pragma unroll
    for (int q = 0; q < NQ; ++q) {
        const float* a = input + ((size_t)b * N + n0 + q * TN) * 3;
        a0[q] = a[0];
        a1[q] = a[1];
        a2[q] = a[2];
        r[q]  = 1e30f;
    }

    // Wave-uniform pointer into the prepped point data for this chunk.
    const float4* __restrict__ wp = w + (size_t)b * M + (size_t)chunk * CHUNK;

    for (int m = 0; m < CHUNK; m += 4) {
        const float4 w0 = wp[m];
        const float4 w1 = wp[m + 1];
        const float4 w2 = wp[m + 2];
        const float4 w3 = wp[m + 3];
#pragma unroll
        for (int q = 0; q < NQ; ++q) {
            float t0 = fmaf(w0.x, a0[q], w0.w);
            t0 = fmaf(w0.y, a1[q], t0);
            t0 = fmaf(w0.z, a2[q], t0);
            float t1 = fmaf(w1.x, a0[q], w1.w);
            t1 = fmaf(w1.y, a1[q], t1);
            t1 = fmaf(w1.z, a2[q], t1);
            float t2 = fmaf(w2.x, a0[q], w2.w);
            t2 = fmaf(w2.y, a1[q], t2);
            t2 = fmaf(w2.z, a2[q], t2);
            float t3 = fmaf(w3.x, a0[q], w3.w);
            t3 = fmaf(w3.y, a1[q], t3);
            t3 = fmaf(w3.z, a2[q], t3);
            r[q] = fminf(r[q], fminf(t0, t1));   // -> v_min3_f32
            r[q] = fminf(r[q], fminf(t2, t3));   // -> v_min3_f32
        }
    }

    // Coalesced plain stores (consecutive tid -> consecutive addresses).
    float* p = partial + (size_t)bid * QB + threadIdx.x;
#pragma unroll
    for (int q = 0; q < NQ; ++q) {
        p[q * TN] = r[q];
    }
}

// ---------------------------------------------------------------------------
// Reduce: one thread per query. min over the 64 chunk-partials (coalesced
// across threads; all L2/L3-resident), then d2 = max(min_r + ||a||^2, 0).
// ---------------------------------------------------------------------------
__global__ __launch_bounds__(256) void reduce_kernel(const float* __restrict__ input,
                                                     const float* __restrict__ partial,
                                                     float* __restrict__ out) {
    const int g = blockIdx.x * 256 + threadIdx.x;   // 0 .. B*N-1
    if (g >= B * N) return;
    const int b     = g / N;
    const int n     = g % N;
    const int ntile = n / QB;
    const int ql    = n % QB;

    const float* p = partial + ((size_t)(b * NTILES + ntile) * CHUNKS) * QB + ql;

    float r = 1e30f;
#pragma unroll
    for (int c = 0; c < CHUNKS; c += 2) {
        r = fminf(r, fminf(p[(size_t)c * QB], p[(size_t)(c + 1) * QB]));
    }

    const float* a = input + (size_t)g * 3;
    const float sq_in = fmaf(a[0], a[0], fmaf(a[1], a[1], a[2] * a[2]));
    out[g] = fmaxf(r + sq_in, 0.0f);
}

extern "C" void kernel_launch(void* const* d_in, const int* in_sizes, int n_in,
                              void* d_out, int out_size, void* d_ws, size_t ws_size,
                              hipStream_t stream) {
    const float* input = (const float*)d_in[0];   // [B, N, 3] fp32
    const float* point = (const float*)d_in[1];   // [B, M, 3] fp32
    float* out         = (float*)d_out;           // [B, N] fp32

    float4* w      = (float4*)d_ws;
    float* partial = (float*)((char*)d_ws + W_BYTES);

    const int prep_grid   = (B * M + 255) / 256;   // 128 blocks
    const int main_grid   = NPART;                 // 2048 blocks
    const int reduce_grid = (B * N + 255) / 256;   // 128 blocks

    prep_kernel<<<prep_grid, 256, 0, stream>>>(point, w);
    main_kernel<<<main_grid, 256, 0, stream>>>(input, w, partial);
    reduce_kernel<<<reduce_grid, 256, 0, stream>>>(input, partial, out);
}

// Round 5
// 76.832 us; speedup vs baseline: 1.1540x; 1.1540x over previous
//
#include <hip/hip_runtime.h>
#include <hip/hip_bf16.h>

// Problem constants (from setup_inputs): B=4, N=8192, M=8192, D=3, fp32.
constexpr int B = 4;
constexpr int N = 8192;
constexpr int M = 8192;

constexpr int TN = 256;              // threads per block
constexpr int NQ = 8;                // queries per thread (registers)
constexpr int QB = TN * NQ;          // 2048 queries per block
constexpr int NTILES = N / QB;       // 4
constexpr int CHUNKS = 128;          // split of M -> grid 2048 = 8 blocks/CU
constexpr int CHUNK = M / CHUNKS;    // 64 points per block (1 KB LDS)

// ---------------------------------------------------------------------------
// Fused kernel. Per block:
//   1. Stage this chunk's w[m] = { -2*px, -2*py, -2*pz, ||p||^2 } into LDS
//      (computed on the fly from `point` — no prep kernel, no global round
//      trip through d_ws, no cross-XCD L2 traffic for the table).
//   2. Each thread holds NQ=8 queries in registers (24 a-components + 8 mins).
//   3. Inner loop: 4 wave-uniform ds_read_b128 (broadcast, conflict-free)
//      amortized over 8 queries -> 112 VALU ops per 32 pairs (3.5/pair).
//   4. d2 = max(min_m(||p||^2 - 2 a.p) + ||a||^2, 0), merged across chunks
//      with atomicMin on the uint view (d2 >= 0 so uint order == float order;
//      out pre-set to 0x7F7F7F7F = 3.39e38f by hipMemsetAsync).
// ---------------------------------------------------------------------------
__global__ __launch_bounds__(256, 8) void main_kernel(const float* __restrict__ input,
                                                      const float* __restrict__ point,
                                                      unsigned int* __restrict__ out) {
    const int bid   = blockIdx.x;
    const int chunk = bid % CHUNKS;
    const int ntile = (bid / CHUNKS) % NTILES;
    const int b     = bid / (CHUNKS * NTILES);
    const int tid   = threadIdx.x;
    const int n0    = ntile * QB + tid;           // queries n0 + q*TN

    __shared__ float4 wlds[CHUNK];

    // Stage the point chunk (first 64 threads, one point each).
    if (tid < CHUNK) {
        const float* p = point + ((size_t)b * M + (size_t)chunk * CHUNK + tid) * 3;
        const float px = p[0], py = p[1], pz = p[2];
        float4 v;
        v.x = -2.0f * px;
        v.y = -2.0f * py;
        v.z = -2.0f * pz;
        v.w = fmaf(px, px, fmaf(py, py, pz * pz));
        wlds[tid] = v;
    }

    // Load this thread's 8 queries while the staging settles.
    float a0[NQ], a1[NQ], a2[NQ], r[NQ];
#pragma unroll
    for (int q = 0; q < NQ; ++q) {
        const float* a = input + ((size_t)b * N + n0 + q * TN) * 3;
        a0[q] = a[0];
        a1[q] = a[1];
        a2[q] = a[2];
        r[q]  = 1e30f;
    }

    __syncthreads();

    for (int m = 0; m < CHUNK; m += 4) {
        const float4 w0 = wlds[m];
        const float4 w1 = wlds[m + 1];
        const float4 w2 = wlds[m + 2];
        const float4 w3 = wlds[m + 3];
#pragma unroll
        for (int q = 0; q < NQ; ++q) {
            float t0 = fmaf(w0.x, a0[q], w0.w);
            t0 = fmaf(w0.y, a1[q], t0);
            t0 = fmaf(w0.z, a2[q], t0);
            float t1 = fmaf(w1.x, a0[q], w1.w);
            t1 = fmaf(w1.y, a1[q], t1);
            t1 = fmaf(w1.z, a2[q], t1);
            float t2 = fmaf(w2.x, a0[q], w2.w);
            t2 = fmaf(w2.y, a1[q], t2);
            t2 = fmaf(w2.z, a2[q], t2);
            float t3 = fmaf(w3.x, a0[q], w3.w);
            t3 = fmaf(w3.y, a1[q], t3);
            t3 = fmaf(w3.z, a2[q], t3);
            r[q] = fminf(r[q], fminf(t0, t1));   // -> v_min3_f32
            r[q] = fminf(r[q], fminf(t2, t3));   // -> v_min3_f32
        }
    }

#pragma unroll
    for (int q = 0; q < NQ; ++q) {
        const float sq_in = fmaf(a0[q], a0[q], fmaf(a1[q], a1[q], a2[q] * a2[q]));
        float d2 = fmaxf(r[q] + sq_in, 0.0f);
        atomicMin(&out[(size_t)b * N + n0 + q * TN], __float_as_uint(d2));
    }
}

extern "C" void kernel_launch(void* const* d_in, const int* in_sizes, int n_in,
                              void* d_out, int out_size, void* d_ws, size_t ws_size,
                              hipStream_t stream) {
    const float* input = (const float*)d_in[0];   // [B, N, 3] fp32
    const float* point = (const float*)d_in[1];   // [B, M, 3] fp32
    unsigned int* out  = (unsigned int*)d_out;    // [B, N] fp32 viewed as uint

    // Init output to 0x7F7F7F7F (3.39e38f). For non-negative floats the uint
    // ordering matches float ordering, so atomicMin(uint) == float min.
    (void)hipMemsetAsync(d_out, 0x7F, (size_t)out_size * sizeof(float), stream);

    const int main_grid = B * NTILES * CHUNKS;    // 2048 blocks
    main_kernel<<<main_grid, 256, 0, stream>>>(input, point, out);
}